// Round 2
// baseline (183.788 us; speedup 1.0000x reference)
//
#include <hip/hip_runtime.h>

// ---------------------------------------------------------------------------
// capsule_87840671138361: conv->routing->attention->fusion, MI355X (gfx950)
// R9 changes vs R8:
//  - attn: REVERTED to R7 (Q persistent in regs). R8's Q-reload was neutral
//    on steady-state (51.3 vs 50.7) but added 87MB L2-miss traffic and a
//    140us cold first dispatch -> net regression. R8 lesson kept: attn is
//    per-CU-shared-resource bound (2x TLP gave 0x speedup), so leave it.
//  - fusion_gemm: double-buffered LDS (48KB) + minimum-2-phase schedule:
//    one raw s_barrier/K-step, own-wave vmcnt(0) before barrier, STAGE(t+1)
//    issued after barrier so DMA overlaps compute(t). Old loop exposed the
//    full DMA latency every one of 16 K-steps (2x __syncthreads drain).
//  - conv_route: 2 half-waves per position (lane owns 4 ch, not 8). All
//    per-lane arrays halve (~150 -> ~95 VGPR -> 4 waves/SIMD), load chains
//    halve, 2x waves. Gram sums combined across halves via 12-float LDS.
// ---------------------------------------------------------------------------

typedef short     bf16x8 __attribute__((ext_vector_type(8)));  // MFMA A/B frag
typedef float     f32x4  __attribute__((ext_vector_type(4)));  // MFMA C/D frag
typedef unsigned short u16;
typedef u16       u16x8  __attribute__((ext_vector_type(8)));
typedef u16       u16x4  __attribute__((ext_vector_type(4)));

#define NBATCH 8
#define LSEQ   2048
#define DCH    512
#define DPAD   520      // padded global row stride (elems): 1040B
#define VSTR   40       // Vs LDS row stride (u16): 80B -> bank-even b128
#define DECAYF 0.2f
#define WTILES 4        // 64-key min window; truncated mass ~4e-5 relative

typedef const __attribute__((address_space(1))) unsigned char* gas_t;
typedef __attribute__((address_space(3))) unsigned char* las_t;
__device__ __forceinline__ void dma16(const void* g, void* l) {
    __builtin_amdgcn_global_load_lds((gas_t)g, (las_t)l, 16, 0, 0);
}

__device__ __forceinline__ u16 f2bf(float f) {
    unsigned int u = __float_as_uint(f);
    u += 0x7fffu + ((u >> 16) & 1u);   // RNE; inputs never NaN
    return (u16)(u >> 16);
}

__device__ __forceinline__ void wave_sum6(float& a, float& b, float& c,
                                          float& d, float& e, float& f) {
#pragma unroll
    for (int m = 1; m < 64; m <<= 1) {
        float ta = __shfl_xor(a, m, 64);
        float tb = __shfl_xor(b, m, 64);
        float tc = __shfl_xor(c, m, 64);
        float td = __shfl_xor(d, m, 64);
        float te = __shfl_xor(e, m, 64);
        float tf = __shfl_xor(f, m, 64);
        a += ta; b += tb; c += tc; d += td; e += te; f += tf;
    }
}

// ---------------------------------------------------------------------------
// Kernel 1: causal depthwise conv (k=3,5) + 2x dynamic routing via Gram dots.
// R9: two half-waves per (n,l); lane owns 4 channels. Halves every per-lane
// array (VGPR ~95 -> 4 waves/SIMD) and halves the global-load chain.
// Cross-half Gram-sum combine via LDS; scalar routing duplicated per wave.
// ---------------------------------------------------------------------------
__global__ __launch_bounds__(256) void conv_route(
    const float* __restrict__ x, const float* __restrict__ w3, const float* __restrict__ w5,
    u16* __restrict__ vs, u16* __restrict__ vt)
{
    const int wid  = threadIdx.x >> 6;           // 0..3
    const int lane = threadIdx.x & 63;
    const int pp   = wid >> 1;                   // position within block (0..1)
    const int half = wid & 1;                    // channel half
    const int p = blockIdx.x * 2 + pp;           // 16384 positions
    const int n = p >> 11, l = p & (LSEQ - 1);
    const int c0 = half * 256 + lane * 4;

    float xm[5][4];                              // xm[j][i] = x[l-j][c0+i]
#pragma unroll
    for (int j = 0; j < 5; ++j) {
        int ll = l - j;
        if (ll >= 0) {                           // wave-uniform branch
            float4 a = *(const float4*)(x + ((size_t)(n*LSEQ + ll))*DCH + c0);
            xm[j][0]=a.x; xm[j][1]=a.y; xm[j][2]=a.z; xm[j][3]=a.w;
        } else {
#pragma unroll
            for (int i = 0; i < 4; ++i) xm[j][i] = 0.f;
        }
    }
    float f3[12], f5[20];
#pragma unroll
    for (int k = 0; k < 3; ++k) ((float4*)f3)[k] = ((const float4*)(w3 + (size_t)c0*3))[k];
#pragma unroll
    for (int k = 0; k < 5; ++k) ((float4*)f5)[k] = ((const float4*)(w5 + (size_t)c0*5))[k];

    float t3[4], t5[4], a0[4], a1[4];
#pragma unroll
    for (int i = 0; i < 4; ++i) {
        t3[i] = f3[i*3+0]*xm[2][i] + f3[i*3+1]*xm[1][i] + f3[i*3+2]*xm[0][i];
        t5[i] = f5[i*5+0]*xm[4][i] + f5[i*5+1]*xm[3][i] + f5[i*5+2]*xm[2][i]
              + f5[i*5+3]*xm[1][i] + f5[i*5+4]*xm[0][i];
        a0[i] = xm[0][i] - t3[i];
        a1[i] = xm[0][i] - t5[i];
    }

    float A1=0.f, B1=0.f, C1=0.f, A2=0.f, B2=0.f, C2=0.f;
#pragma unroll
    for (int i = 0; i < 4; ++i) {
        A1 += a0[i]*a0[i]; B1 += a0[i]*a1[i]; C1 += a1[i]*a1[i];
        A2 += t3[i]*t3[i]; B2 += t3[i]*t5[i]; C2 += t5[i]*t5[i];
    }
    wave_sum6(A1, B1, C1, A2, B2, C2);

    // combine the two channel-halves' Gram sums
    __shared__ float red[2][2][6];
    if (lane == 0) {
        red[pp][half][0] = A1; red[pp][half][1] = B1; red[pp][half][2] = C1;
        red[pp][half][3] = A2; red[pp][half][4] = B2; red[pp][half][5] = C2;
    }
    __syncthreads();
    A1 = red[pp][0][0] + red[pp][1][0];
    B1 = red[pp][0][1] + red[pp][1][1];
    C1 = red[pp][0][2] + red[pp][1][2];
    A2 = red[pp][0][3] + red[pp][1][3];
    B2 = red[pp][0][4] + red[pp][1][4];
    C2 = red[pp][0][5] + red[pp][1][5];

    float ba0=0.f, ba1=0.f, bb0=0.f, bb1=0.f;
    float ca0=0.5f, ca1=0.5f, sca=0.f, cb0=0.5f, cb1=0.5f, scb=0.f;
#pragma unroll
    for (int it = 0; it < 3; ++it) {
        float mxa = fmaxf(ba0, ba1), mxb = fmaxf(bb0, bb1);
        float ea0 = __expf(ba0-mxa), ea1 = __expf(ba1-mxa);
        float eb0 = __expf(bb0-mxb), eb1 = __expf(bb1-mxb);
        float ia = 1.f/(ea0+ea1), ib = 1.f/(eb0+eb1);
        ca0 = ea0*ia; ca1 = ea1*ia; cb0 = eb0*ib; cb1 = eb1*ib;
        float na = ca0*ca0*A1 + 2.f*ca0*ca1*B1 + ca1*ca1*C1;
        float nb = cb0*cb0*A2 + 2.f*cb0*cb1*B2 + cb1*cb1*C2;
        sca = na / ((1.f + na) * (sqrtf(na) + 1e-9f));
        scb = nb / ((1.f + nb) * (sqrtf(nb) + 1e-9f));
        if (it < 2) {
            ba0 += sca*(ca0*A1 + ca1*B1);
            ba1 += sca*(ca0*B1 + ca1*C1);
            bb0 += scb*(cb0*A2 + cb1*B2);
            bb1 += scb*(cb0*B2 + cb1*C2);
        }
    }
    u16x4 pa, pb;
#pragma unroll
    for (int i = 0; i < 4; ++i) {
        pa[i] = f2bf(sca*(ca0*a0[i] + ca1*a1[i]));
        pb[i] = f2bf(scb*(cb0*t3[i] + cb1*t5[i]));
    }
    *(u16x4*)(vs + (size_t)p*DPAD + c0) = pa;
    *(u16x4*)(vt + (size_t)p*DPAD + c0) = pb;
}

// ---------------------------------------------------------------------------
// Kernel 2: windowed causal attention; V^T built in-LDS from Ks. (R7 form.)
// grid (32 strips, 16 instances), 256 threads (4 waves), 64 q-rows/block.
// ---------------------------------------------------------------------------
__global__ __launch_bounds__(256) void attn(
    const u16* __restrict__ vs, const u16* __restrict__ vt,
    u16* __restrict__ cat)
{
    __shared__ u16 Ks[33792/2];              // 32 rows x 1040B + DMA slack
    __shared__ u16 Vs[DCH*VSTR];             // 40 KB, [ch][40] slot-interleaved
    __shared__ unsigned int Ps32[4][16][20]; // per-wave P, packed pairs

    const int inst = blockIdx.y;
    const int t = inst >> 3, n = inst & 7;
    const u16* src = (t ? vt : vs) + (size_t)n * LSEQ * DPAD;

    const int bx = blockIdx.x;
    const int r0 = (((bx & 7) << 2) | (bx >> 3)) * 64;   // XCD swizzle

    const int tid  = threadIdx.x;
    const int wid  = tid >> 6, lane = tid & 63;
    const int l16  = lane & 15, quad = lane >> 4;

    // Q A-frags register-resident
    bf16x8 qf[16];
    {
        const u16* qp = src + (size_t)(r0 + wid*16 + l16) * DPAD + quad*8;
#pragma unroll
        for (int kc = 0; kc < 16; ++kc) qf[kc] = *(const bf16x8*)(qp + kc*32);
    }

    f32x4 O[32];
#pragma unroll
    for (int i = 0; i < 32; ++i) O[i] = (f32x4){0.f, 0.f, 0.f, 0.f};
    f32x4 O2 = {0.f, 0.f, 0.f, 0.f};       // row sums via ones-MFMA

    bf16x8 ones8;
#pragma unroll
    for (int i = 0; i < 8; ++i) ones8[i] = (short)0x3F80;   // bf16 1.0

    const int kb_hi = (r0 >> 5) + 1;
    const int kb_lo = (kb_hi >= WTILES) ? kb_hi - (WTILES-1) : 0;

    // prologue: K(kb_lo) in flight
    {
        const u16* gK = src + (size_t)kb_lo * 32 * DPAD;
        for (int i = wid; i < 33; i += 4) dma16(gK + i*512 + lane*8, Ks + i*512);
    }

    for (int kb = kb_lo; kb <= kb_hi; ++kb) {
        __syncthreads();   // K(kb) drained; prev Phase B done with Vs

        // Phase A: S[16x32] = Q * K^T, 4 independent 8-deep chains
        f32x4 S0a = {0.f,0.f,0.f,0.f}, S1a = {0.f,0.f,0.f,0.f};
        f32x4 S0b = {0.f,0.f,0.f,0.f}, S1b = {0.f,0.f,0.f,0.f};
#pragma unroll
        for (int kc = 0; kc < 8; ++kc) {
            bf16x8 b0 = *(const bf16x8*)(Ks + (size_t)l16*DPAD + kc*32 + quad*8);
            bf16x8 b1 = *(const bf16x8*)(Ks + (size_t)(16+l16)*DPAD + kc*32 + quad*8);
            S0a = __builtin_amdgcn_mfma_f32_16x16x32_bf16(qf[kc], b0, S0a, 0, 0, 0);
            S1a = __builtin_amdgcn_mfma_f32_16x16x32_bf16(qf[kc], b1, S1a, 0, 0, 0);
        }
#pragma unroll
        for (int kc = 8; kc < 16; ++kc) {
            bf16x8 b0 = *(const bf16x8*)(Ks + (size_t)l16*DPAD + kc*32 + quad*8);
            bf16x8 b1 = *(const bf16x8*)(Ks + (size_t)(16+l16)*DPAD + kc*32 + quad*8);
            S0b = __builtin_amdgcn_mfma_f32_16x16x32_bf16(qf[kc], b0, S0b, 0, 0, 0);
            S1b = __builtin_amdgcn_mfma_f32_16x16x32_bf16(qf[kc], b1, S1b, 0, 0, 0);
        }
        f32x4 S0 = S0a + S0b, S1 = S1a + S1b;

        // in-LDS transpose: Ks rows -> Vs[ch][40], slot s <- key (s>>1)+16(s&1)
#pragma unroll
        for (int pass = 0; pass < 2; ++pass) {
            const int ch = pass*256 + tid;
#pragma unroll
            for (int g = 0; g < 4; ++g) {
                u16x8 o;
#pragma unroll
                for (int j = 0; j < 4; ++j) {
                    o[2*j]   = Ks[(size_t)(g*4 + j)      * DPAD + ch];
                    o[2*j+1] = Ks[(size_t)(g*4 + j + 16) * DPAD + ch];
                }
                *(u16x8*)(Vs + ch*VSTR + g*8) = o;
            }
        }

        // fixed-max softmax: p = exp(s - 1 - 0.2*d), zero outside causal window
        const int rowg = r0 + wid*16 + quad*4;
#pragma unroll
        for (int r = 0; r < 4; ++r) {
            int row = rowg + r;
            int d0  = row - (kb*32 + l16);
            int d1  = d0 - 16;
            float p0 = (d0 >= 0) ? __expf(fmaf(-DECAYF, (float)d0, S0[r] - 1.f)) : 0.f;
            float p1 = (d1 >= 0) ? __expf(fmaf(-DECAYF, (float)d1, S1[r] - 1.f)) : 0.f;
            Ps32[wid][quad*4 + r][l16] = ((unsigned)f2bf(p1) << 16) | (unsigned)f2bf(p0);
        }

        __syncthreads();   // Vs complete; all waves done with Ks
        // K(kb+1) DMA overlaps Phase B
        if (kb < kb_hi) {
            const u16* gK = src + (size_t)(kb+1) * 32 * DPAD;
            for (int i = wid; i < 33; i += 4) dma16(gK + i*512 + lane*8, Ks + i*512);
        }

        // Phase B: O += P * V (slot-interleaved, consistent in Ps & Vs)
        bf16x8 pf = *(const bf16x8*)(&Ps32[wid][l16][quad*4]);
#pragma unroll
        for (int ct = 0; ct < 32; ++ct) {
            bf16x8 vf = *(const bf16x8*)(Vs + (size_t)(ct*16 + l16)*VSTR + quad*8);
            O[ct] = __builtin_amdgcn_mfma_f32_16x16x32_bf16(pf, vf, O[ct], 0, 0, 0);
        }
        O2 = __builtin_amdgcn_mfma_f32_16x16x32_bf16(pf, ones8, O2, 0, 0, 0);
    }

    // epilogue: O /= rowsum, write bf16 into cat
    float inv[4];
#pragma unroll
    for (int r = 0; r < 4; ++r) inv[r] = 1.f / O2[r];
    const size_t rowbase = (size_t)n * LSEQ + r0 + wid*16 + quad*4;
    const int colbase = t * 512 + l16;
#pragma unroll
    for (int ct = 0; ct < 32; ++ct) {
#pragma unroll
        for (int r = 0; r < 4; ++r)
            cat[(rowbase + r) * 1024 + colbase + ct*16] = f2bf(O[ct][r] * inv[r]);
    }
}

// ---------------------------------------------------------------------------
// Kernel 3: cast fusion_w fp32 -> bf16
// ---------------------------------------------------------------------------
__global__ __launch_bounds__(256) void cast_w(const float* __restrict__ w, u16* __restrict__ wb)
{
    int id = blockIdx.x * 256 + threadIdx.x;   // 131072 float4 chunks
    float4 f = ((const float4*)w)[id];
    u16x4 o;
    o[0] = f2bf(f.x); o[1] = f2bf(f.y); o[2] = f2bf(f.z); o[3] = f2bf(f.w);
    ((u16x4*)wb)[id] = o;
}

// ---------------------------------------------------------------------------
// Kernel 4: out[16384,512] = cat @ W^T + bias. 64x128 tiles, BK=64,
// dma16 staging with XOR-swizzled chunk mapping (swizzle via source addr).
// R9: double-buffered LDS, single raw s_barrier per K-step, own-wave
// vmcnt(0) before barrier, STAGE(t+1) after barrier overlapping compute(t).
// ---------------------------------------------------------------------------
__global__ __launch_bounds__(256) void fusion_gemm(
    const u16* __restrict__ A, const u16* __restrict__ Wb,
    const float* __restrict__ bias, float* __restrict__ out)
{
    __shared__ u16 As[2][64*64];    // 16 KB
    __shared__ u16 Bs[2][128*64];   // 32 KB
    const int m0 = blockIdx.x * 64;
    const int n0 = blockIdx.y * 128;
    const int tid = threadIdx.x;
    const int wid = tid >> 6, lane = tid & 63;
    const int l16 = lane & 15, quad = lane >> 4;

    f32x4 acc[4][2];
#pragma unroll
    for (int i = 0; i < 4; ++i)
#pragma unroll
        for (int j = 0; j < 2; ++j) acc[i][j] = (f32x4){0.f, 0.f, 0.f, 0.f};

    auto stage = [&](int kb_, int b_) {
#pragma unroll
        for (int i = 0; i < 2; ++i) {
            int q = i*256 + tid, r = q >> 3, kp = q & 7;
            int kl = kp ^ (r & 7);
            dma16(A + (size_t)(m0 + r)*1024 + kb_*64 + kl*8, As[b_] + q*8);
        }
#pragma unroll
        for (int i = 0; i < 4; ++i) {
            int q = i*256 + tid, r = q >> 3, kp = q & 7;
            int kl = kp ^ (r & 7);
            dma16(Wb + (size_t)(n0 + r)*1024 + kb_*64 + kl*8, Bs[b_] + q*8);
        }
    };

    stage(0, 0);
    for (int kb = 0; kb < 16; ++kb) {
        const int b = kb & 1;
        // own tile-kb DMAs complete (only tile kb outstanding here)
        asm volatile("s_waitcnt vmcnt(0)" ::: "memory");
        __builtin_amdgcn_s_barrier();          // all waves' kb-DMA landed;
        asm volatile("" ::: "memory");         //   all done reading buf b^1
        if (kb < 15) stage(kb + 1, b ^ 1);     // overlaps compute below
#pragma unroll
        for (int k2 = 0; k2 < 2; ++k2) {
            const int kl = k2*4 + quad;
            bf16x8 af[4], bf2[2];
#pragma unroll
            for (int i = 0; i < 4; ++i) {
                int r = i*16 + l16;
                af[i] = *(const bf16x8*)(As[b] + r*64 + (kl ^ (r & 7))*8);
            }
#pragma unroll
            for (int j = 0; j < 2; ++j) {
                int r = wid*32 + j*16 + l16;
                bf2[j] = *(const bf16x8*)(Bs[b] + r*64 + (kl ^ (r & 7))*8);
            }
#pragma unroll
            for (int i = 0; i < 4; ++i)
#pragma unroll
                for (int j = 0; j < 2; ++j)
                    acc[i][j] = __builtin_amdgcn_mfma_f32_16x16x32_bf16(af[i], bf2[j], acc[i][j], 0, 0, 0);
        }
    }
#pragma unroll
    for (int j = 0; j < 2; ++j) {
        int col = n0 + wid*32 + j*16 + l16;
        float bv = bias[col];
#pragma unroll
        for (int i = 0; i < 4; ++i) {
            int rowb = m0 + i*16 + quad*4;
#pragma unroll
            for (int r = 0; r < 4; ++r)
                out[(size_t)(rowb + r)*512 + col] = acc[i][j][r] + bv;
        }
    }
}

// ---------------------------------------------------------------------------
extern "C" void kernel_launch(void* const* d_in, const int* in_sizes, int n_in,
                              void* d_out, int out_size, void* d_ws, size_t ws_size,
                              hipStream_t stream)
{
    (void)in_sizes; (void)n_in; (void)out_size; (void)ws_size;
    const float* x  = (const float*)d_in[0];
    const float* w3 = (const float*)d_in[1];
    const float* w5 = (const float*)d_in[2];
    const float* fw = (const float*)d_in[3];
    const float* fb = (const float*)d_in[4];
    float* out = (float*)d_out;

    const size_t SZP = (size_t)NBATCH * LSEQ * DPAD;    // padded rows
    u16* vs   = (u16*)d_ws;        // [N][L][520]
    u16* vt   = vs   + SZP;
    u16* cat  = vt   + SZP;        // [N*L][1024]
    u16* wb   = cat  + (size_t)NBATCH*LSEQ*1024;   // [512][1024] bf16

    cast_w     <<<512, 256, 0, stream>>>(fw, wb);
    conv_route <<<8192, 256, 0, stream>>>(x, w3, w5, vs, vt);
    attn       <<<dim3(32, 16), 256, 0, stream>>>(vs, vt, cat);
    fusion_gemm<<<dim3(256, 4), 256, 0, stream>>>(cat, wb, fb, out);
}

// Round 4
// 177.345 us; speedup vs baseline: 1.0363x; 1.0363x over previous
//
#include <hip/hip_runtime.h>

// ---------------------------------------------------------------------------
// capsule_87840671138361: conv->routing->attention->fusion, MI355X (gfx950)
// R11 = R10 resubmit (container failed twice, no counters) with the single
// memory-safety blemish closed:
//  - attn stageK: chunks 33..35 (tile is 32.5 chunks) now re-read chunk 0
//    instead of running 3.5KB past the tile end (last vt tile read past the
//    vt allocation into cat). Source always in-tile; dest = LDS slack that
//    is never read. Keeps uniform 9 loads/wave for the counted vmcnt(9).
// R10 changes vs R9 (untested, carried forward):
//  - fusion_gemm: depth-2 prefetch. 3 LDS buffers (72KB), counted
//    s_waitcnt vmcnt(6) at loop top (drains tile kb, leaves kb+1 in
//    flight), stage(kb+2) after barrier. R9's depth-1 exposed ~(lat-compute)
//    every K-step (42us, MfmaUtil 14.5%, nothing saturated).
//  - attn: Ks double-buffered (2x36KB) + counted vmcnt(9) + raw s_barrier.
//    Old __syncthreads() forced a full vmcnt(0) drain of the K prefetch
//    every tile. In-LDS transpose reads paired b32 (32 reads + pack)
//    instead of 64 scalar u16 reads.
//  - conv_route / cast_w unchanged from R9.
// ---------------------------------------------------------------------------

typedef short     bf16x8 __attribute__((ext_vector_type(8)));  // MFMA A/B frag
typedef float     f32x4  __attribute__((ext_vector_type(4)));  // MFMA C/D frag
typedef unsigned short u16;
typedef u16       u16x8  __attribute__((ext_vector_type(8)));
typedef u16       u16x4  __attribute__((ext_vector_type(4)));
typedef unsigned int u32;
typedef u32       u32x4  __attribute__((ext_vector_type(4)));

#define NBATCH 8
#define LSEQ   2048
#define DCH    512
#define DPAD   520      // padded global row stride (elems): 1040B
#define VSTR   40       // Vs LDS row stride (u16): 80B -> bank-even b128
#define DECAYF 0.2f
#define WTILES 4        // 64-key min window; truncated mass ~4e-5 relative

typedef const __attribute__((address_space(1))) unsigned char* gas_t;
typedef __attribute__((address_space(3))) unsigned char* las_t;
__device__ __forceinline__ void dma16(const void* g, void* l) {
    __builtin_amdgcn_global_load_lds((gas_t)g, (las_t)l, 16, 0, 0);
}

__device__ __forceinline__ u16 f2bf(float f) {
    unsigned int u = __float_as_uint(f);
    u += 0x7fffu + ((u >> 16) & 1u);   // RNE; inputs never NaN
    return (u16)(u >> 16);
}

__device__ __forceinline__ void wave_sum6(float& a, float& b, float& c,
                                          float& d, float& e, float& f) {
#pragma unroll
    for (int m = 1; m < 64; m <<= 1) {
        float ta = __shfl_xor(a, m, 64);
        float tb = __shfl_xor(b, m, 64);
        float tc = __shfl_xor(c, m, 64);
        float td = __shfl_xor(d, m, 64);
        float te = __shfl_xor(e, m, 64);
        float tf = __shfl_xor(f, m, 64);
        a += ta; b += tb; c += tc; d += td; e += te; f += tf;
    }
}

// ---------------------------------------------------------------------------
// Kernel 1: causal depthwise conv (k=3,5) + 2x dynamic routing via Gram dots.
// Two half-waves per (n,l); lane owns 4 channels (R9 form).
// ---------------------------------------------------------------------------
__global__ __launch_bounds__(256) void conv_route(
    const float* __restrict__ x, const float* __restrict__ w3, const float* __restrict__ w5,
    u16* __restrict__ vs, u16* __restrict__ vt)
{
    const int wid  = threadIdx.x >> 6;           // 0..3
    const int lane = threadIdx.x & 63;
    const int pp   = wid >> 1;                   // position within block (0..1)
    const int half = wid & 1;                    // channel half
    const int p = blockIdx.x * 2 + pp;           // 16384 positions
    const int n = p >> 11, l = p & (LSEQ - 1);
    const int c0 = half * 256 + lane * 4;

    float xm[5][4];                              // xm[j][i] = x[l-j][c0+i]
#pragma unroll
    for (int j = 0; j < 5; ++j) {
        int ll = l - j;
        if (ll >= 0) {                           // wave-uniform branch
            float4 a = *(const float4*)(x + ((size_t)(n*LSEQ + ll))*DCH + c0);
            xm[j][0]=a.x; xm[j][1]=a.y; xm[j][2]=a.z; xm[j][3]=a.w;
        } else {
#pragma unroll
            for (int i = 0; i < 4; ++i) xm[j][i] = 0.f;
        }
    }
    float f3[12], f5[20];
#pragma unroll
    for (int k = 0; k < 3; ++k) ((float4*)f3)[k] = ((const float4*)(w3 + (size_t)c0*3))[k];
#pragma unroll
    for (int k = 0; k < 5; ++k) ((float4*)f5)[k] = ((const float4*)(w5 + (size_t)c0*5))[k];

    float t3[4], t5[4], a0[4], a1[4];
#pragma unroll
    for (int i = 0; i < 4; ++i) {
        t3[i] = f3[i*3+0]*xm[2][i] + f3[i*3+1]*xm[1][i] + f3[i*3+2]*xm[0][i];
        t5[i] = f5[i*5+0]*xm[4][i] + f5[i*5+1]*xm[3][i] + f5[i*5+2]*xm[2][i]
              + f5[i*5+3]*xm[1][i] + f5[i*5+4]*xm[0][i];
        a0[i] = xm[0][i] - t3[i];
        a1[i] = xm[0][i] - t5[i];
    }

    float A1=0.f, B1=0.f, C1=0.f, A2=0.f, B2=0.f, C2=0.f;
#pragma unroll
    for (int i = 0; i < 4; ++i) {
        A1 += a0[i]*a0[i]; B1 += a0[i]*a1[i]; C1 += a1[i]*a1[i];
        A2 += t3[i]*t3[i]; B2 += t3[i]*t5[i]; C2 += t5[i]*t5[i];
    }
    wave_sum6(A1, B1, C1, A2, B2, C2);

    // combine the two channel-halves' Gram sums
    __shared__ float red[2][2][6];
    if (lane == 0) {
        red[pp][half][0] = A1; red[pp][half][1] = B1; red[pp][half][2] = C1;
        red[pp][half][3] = A2; red[pp][half][4] = B2; red[pp][half][5] = C2;
    }
    __syncthreads();
    A1 = red[pp][0][0] + red[pp][1][0];
    B1 = red[pp][0][1] + red[pp][1][1];
    C1 = red[pp][0][2] + red[pp][1][2];
    A2 = red[pp][0][3] + red[pp][1][3];
    B2 = red[pp][0][4] + red[pp][1][4];
    C2 = red[pp][0][5] + red[pp][1][5];

    float ba0=0.f, ba1=0.f, bb0=0.f, bb1=0.f;
    float ca0=0.5f, ca1=0.5f, sca=0.f, cb0=0.5f, cb1=0.5f, scb=0.f;
#pragma unroll
    for (int it = 0; it < 3; ++it) {
        float mxa = fmaxf(ba0, ba1), mxb = fmaxf(bb0, bb1);
        float ea0 = __expf(ba0-mxa), ea1 = __expf(ba1-mxa);
        float eb0 = __expf(bb0-mxb), eb1 = __expf(bb1-mxb);
        float ia = 1.f/(ea0+ea1), ib = 1.f/(eb0+eb1);
        ca0 = ea0*ia; ca1 = ea1*ia; cb0 = eb0*ib; cb1 = eb1*ib;
        float na = ca0*ca0*A1 + 2.f*ca0*ca1*B1 + ca1*ca1*C1;
        float nb = cb0*cb0*A2 + 2.f*cb0*cb1*B2 + cb1*cb1*C2;
        sca = na / ((1.f + na) * (sqrtf(na) + 1e-9f));
        scb = nb / ((1.f + nb) * (sqrtf(nb) + 1e-9f));
        if (it < 2) {
            ba0 += sca*(ca0*A1 + ca1*B1);
            ba1 += sca*(ca0*B1 + ca1*C1);
            bb0 += scb*(cb0*A2 + cb1*B2);
            bb1 += scb*(cb0*B2 + cb1*C2);
        }
    }
    u16x4 pa, pb;
#pragma unroll
    for (int i = 0; i < 4; ++i) {
        pa[i] = f2bf(sca*(ca0*a0[i] + ca1*a1[i]));
        pb[i] = f2bf(scb*(cb0*t3[i] + cb1*t5[i]));
    }
    *(u16x4*)(vs + (size_t)p*DPAD + c0) = pa;
    *(u16x4*)(vt + (size_t)p*DPAD + c0) = pb;
}

// ---------------------------------------------------------------------------
// Kernel 2: windowed causal attention; V^T built in-LDS from Ks.
// grid (32 strips, 16 instances), 256 threads (4 waves), 64 q-rows/block.
// R10/R11: Ks double-buffered, counted vmcnt, raw barriers, b32 transpose.
// ---------------------------------------------------------------------------
__global__ __launch_bounds__(256) void attn(
    const u16* __restrict__ vs, const u16* __restrict__ vt,
    u16* __restrict__ cat)
{
    __shared__ u16 KsB[2][18432];            // 2 x 36KB (32 rows x 1040B + slack)
    __shared__ u16 Vs[DCH*VSTR];             // 40 KB, [ch][40] slot-interleaved
    __shared__ unsigned int Ps32[4][16][20]; // per-wave P, packed pairs

    const int inst = blockIdx.y;
    const int t = inst >> 3, n = inst & 7;
    const u16* src = (t ? vt : vs) + (size_t)n * LSEQ * DPAD;

    const int bx = blockIdx.x;
    const int r0 = (((bx & 7) << 2) | (bx >> 3)) * 64;   // XCD swizzle

    const int tid  = threadIdx.x;
    const int wid  = tid >> 6, lane = tid & 63;
    const int l16  = lane & 15, quad = lane >> 4;

    // Q A-frags register-resident
    bf16x8 qf[16];
    {
        const u16* qp = src + (size_t)(r0 + wid*16 + l16) * DPAD + quad*8;
#pragma unroll
        for (int kc = 0; kc < 16; ++kc) qf[kc] = *(const bf16x8*)(qp + kc*32);
    }

    f32x4 O[32];
#pragma unroll
    for (int i = 0; i < 32; ++i) O[i] = (f32x4){0.f, 0.f, 0.f, 0.f};
    f32x4 O2 = {0.f, 0.f, 0.f, 0.f};       // row sums via ones-MFMA

    bf16x8 ones8;
#pragma unroll
    for (int i = 0; i < 8; ++i) ones8[i] = (short)0x3F80;   // bf16 1.0

    const int kb_hi = (r0 >> 5) + 1;
    const int kb_lo = (kb_hi >= WTILES) ? kb_hi - (WTILES-1) : 0;

    // uniform 9 loads/wave; chunks 33..35 re-read chunk 0 (tile = 32.5
    // chunks) so the source never leaves the tile; their LDS dest is slack.
    auto stageK = [&](int kbt, int buf) {
        const u16* gK = src + (size_t)kbt * 32 * DPAD;
#pragma unroll
        for (int j = 0; j < 9; ++j) {
            int i = wid + 4*j;                 // 0..35
            int is = (i < 33) ? i : 0;         // safe source chunk
            dma16(gK + is*512 + lane*8, KsB[buf] + i*512);
        }
    };

    // prologue: K(kb_lo), K(kb_lo+1) in flight (kb_lo+1 <= kb_hi always)
    stageK(kb_lo,     0);
    stageK(kb_lo + 1, 1);

    for (int kb = kb_lo; kb <= kb_hi; ++kb) {
        // drain K(kb) only; K(kb+1) stays in flight across the barrier
        if (kb < kb_hi) asm volatile("s_waitcnt vmcnt(9)" ::: "memory");
        else            asm volatile("s_waitcnt vmcnt(0)" ::: "memory");
        __builtin_amdgcn_s_barrier();          // K(kb) landed for all waves;
        asm volatile("" ::: "memory");         //   prev Phase B done with Vs
        const u16* K = KsB[(kb - kb_lo) & 1];

        // Phase A: S[16x32] = Q * K^T, 4 independent 8-deep chains
        f32x4 S0a = {0.f,0.f,0.f,0.f}, S1a = {0.f,0.f,0.f,0.f};
        f32x4 S0b = {0.f,0.f,0.f,0.f}, S1b = {0.f,0.f,0.f,0.f};
#pragma unroll
        for (int kc = 0; kc < 8; ++kc) {
            bf16x8 b0 = *(const bf16x8*)(K + (size_t)l16*DPAD + kc*32 + quad*8);
            bf16x8 b1 = *(const bf16x8*)(K + (size_t)(16+l16)*DPAD + kc*32 + quad*8);
            S0a = __builtin_amdgcn_mfma_f32_16x16x32_bf16(qf[kc], b0, S0a, 0, 0, 0);
            S1a = __builtin_amdgcn_mfma_f32_16x16x32_bf16(qf[kc], b1, S1a, 0, 0, 0);
        }
#pragma unroll
        for (int kc = 8; kc < 16; ++kc) {
            bf16x8 b0 = *(const bf16x8*)(K + (size_t)l16*DPAD + kc*32 + quad*8);
            bf16x8 b1 = *(const bf16x8*)(K + (size_t)(16+l16)*DPAD + kc*32 + quad*8);
            S0b = __builtin_amdgcn_mfma_f32_16x16x32_bf16(qf[kc], b0, S0b, 0, 0, 0);
            S1b = __builtin_amdgcn_mfma_f32_16x16x32_bf16(qf[kc], b1, S1b, 0, 0, 0);
        }
        f32x4 S0 = S0a + S0b, S1 = S1a + S1b;

        // in-LDS transpose, b32-pair form: thread owns chs {2*tid, 2*tid+1}.
        // 32 ds_read_b32 (conflict-free) + pack + 8 b128 writes per thread
        // (was 64 scalar ds_read_u16). Vs[ch][40]: slot s <- key (s>>1)+16(s&1)
        {
            const int ch2 = tid * 2;
#pragma unroll
            for (int g = 0; g < 4; ++g) {
                u32 pe[4], po[4];
#pragma unroll
                for (int j = 0; j < 4; ++j) {
                    u32 lo = *(const u32*)(K + (size_t)(g*4 + j)      * DPAD + ch2);
                    u32 hi = *(const u32*)(K + (size_t)(g*4 + j + 16) * DPAD + ch2);
                    pe[j] = (lo & 0xffffu) | (hi << 16);
                    po[j] = (lo >> 16)     | (hi & 0xffff0000u);
                }
                *(u32x4*)(Vs + (size_t)ch2*VSTR + g*8)       = (u32x4){pe[0],pe[1],pe[2],pe[3]};
                *(u32x4*)(Vs + (size_t)(ch2+1)*VSTR + g*8)   = (u32x4){po[0],po[1],po[2],po[3]};
            }
        }

        // fixed-max softmax: p = exp(s - 1 - 0.2*d), zero outside causal window
        const int rowg = r0 + wid*16 + quad*4;
#pragma unroll
        for (int r = 0; r < 4; ++r) {
            int row = rowg + r;
            int d0  = row - (kb*32 + l16);
            int d1  = d0 - 16;
            float p0 = (d0 >= 0) ? __expf(fmaf(-DECAYF, (float)d0, S0[r] - 1.f)) : 0.f;
            float p1 = (d1 >= 0) ? __expf(fmaf(-DECAYF, (float)d1, S1[r] - 1.f)) : 0.f;
            Ps32[wid][quad*4 + r][l16] = ((unsigned)f2bf(p1) << 16) | (unsigned)f2bf(p0);
        }

        asm volatile("s_waitcnt lgkmcnt(0)" ::: "memory");  // Vs/Ps writes done
        __builtin_amdgcn_s_barrier();          // Vs complete; Ks[buf] free
        asm volatile("" ::: "memory");
        // K(kb+2) DMA into the buffer just freed; overlaps Phase B + next A
        if (kb + 2 <= kb_hi) stageK(kb + 2, (kb - kb_lo) & 1);

        // Phase B: O += P * V (slot-interleaved, consistent in Ps & Vs)
        bf16x8 pf = *(const bf16x8*)(&Ps32[wid][l16][quad*4]);
#pragma unroll
        for (int ct = 0; ct < 32; ++ct) {
            bf16x8 vf = *(const bf16x8*)(Vs + (size_t)(ct*16 + l16)*VSTR + quad*8);
            O[ct] = __builtin_amdgcn_mfma_f32_16x16x32_bf16(pf, vf, O[ct], 0, 0, 0);
        }
        O2 = __builtin_amdgcn_mfma_f32_16x16x32_bf16(pf, ones8, O2, 0, 0, 0);
    }

    // epilogue: O /= rowsum, write bf16 into cat
    float inv[4];
#pragma unroll
    for (int r = 0; r < 4; ++r) inv[r] = 1.f / O2[r];
    const size_t rowbase = (size_t)n * LSEQ + r0 + wid*16 + quad*4;
    const int colbase = t * 512 + l16;
#pragma unroll
    for (int ct = 0; ct < 32; ++ct) {
#pragma unroll
        for (int r = 0; r < 4; ++r)
            cat[(rowbase + r) * 1024 + colbase + ct*16] = f2bf(O[ct][r] * inv[r]);
    }
}

// ---------------------------------------------------------------------------
// Kernel 3: cast fusion_w fp32 -> bf16
// ---------------------------------------------------------------------------
__global__ __launch_bounds__(256) void cast_w(const float* __restrict__ w, u16* __restrict__ wb)
{
    int id = blockIdx.x * 256 + threadIdx.x;   // 131072 float4 chunks
    float4 f = ((const float4*)w)[id];
    u16x4 o;
    o[0] = f2bf(f.x); o[1] = f2bf(f.y); o[2] = f2bf(f.z); o[3] = f2bf(f.w);
    ((u16x4*)wb)[id] = o;
}

// ---------------------------------------------------------------------------
// Kernel 4: out[16384,512] = cat @ W^T + bias. 64x128 tiles, BK=64,
// dma16 staging with XOR-swizzled chunk mapping (swizzle via source addr).
// R10/R11: depth-2 prefetch, 3 buffers, counted vmcnt(6) (never 0 mid-loop).
// ---------------------------------------------------------------------------
__global__ __launch_bounds__(256) void fusion_gemm(
    const u16* __restrict__ A, const u16* __restrict__ Wb,
    const float* __restrict__ bias, float* __restrict__ out)
{
    __shared__ u16 As[3][64*64];    // 24 KB
    __shared__ u16 Bs[3][128*64];   // 48 KB
    const int m0 = blockIdx.x * 64;
    const int n0 = blockIdx.y * 128;
    const int tid = threadIdx.x;
    const int wid = tid >> 6, lane = tid & 63;
    const int l16 = lane & 15, quad = lane >> 4;

    f32x4 acc[4][2];
#pragma unroll
    for (int i = 0; i < 4; ++i)
#pragma unroll
        for (int j = 0; j < 2; ++j) acc[i][j] = (f32x4){0.f, 0.f, 0.f, 0.f};

    auto stage = [&](int kb_, int b_) {        // 6 dma16 per wave
#pragma unroll
        for (int i = 0; i < 2; ++i) {
            int q = i*256 + tid, r = q >> 3, kp = q & 7;
            int kl = kp ^ (r & 7);
            dma16(A + (size_t)(m0 + r)*1024 + kb_*64 + kl*8, As[b_] + q*8);
        }
#pragma unroll
        for (int i = 0; i < 4; ++i) {
            int q = i*256 + tid, r = q >> 3, kp = q & 7;
            int kl = kp ^ (r & 7);
            dma16(Wb + (size_t)(n0 + r)*1024 + kb_*64 + kl*8, Bs[b_] + q*8);
        }
    };

    stage(0, 0);
    stage(1, 1);
    for (int kb = 0; kb < 16; ++kb) {
        const int b = kb % 3;
        // drain tile kb's 6 loads; leave tile kb+1's 6 in flight
        if (kb < 15) asm volatile("s_waitcnt vmcnt(6)" ::: "memory");
        else         asm volatile("s_waitcnt vmcnt(0)" ::: "memory");
        __builtin_amdgcn_s_barrier();          // all waves' kb-DMA landed;
        asm volatile("" ::: "memory");         //   all done reading buf kb-1
        if (kb < 14) stage(kb + 2, (kb + 2) % 3);   // overlaps 2 compute phases
#pragma unroll
        for (int k2 = 0; k2 < 2; ++k2) {
            const int kl = k2*4 + quad;
            bf16x8 af[4], bf2[2];
#pragma unroll
            for (int i = 0; i < 4; ++i) {
                int r = i*16 + l16;
                af[i] = *(const bf16x8*)(As[b] + r*64 + (kl ^ (r & 7))*8);
            }
#pragma unroll
            for (int j = 0; j < 2; ++j) {
                int r = wid*32 + j*16 + l16;
                bf2[j] = *(const bf16x8*)(Bs[b] + r*64 + (kl ^ (r & 7))*8);
            }
#pragma unroll
            for (int i = 0; i < 4; ++i)
#pragma unroll
                for (int j = 0; j < 2; ++j)
                    acc[i][j] = __builtin_amdgcn_mfma_f32_16x16x32_bf16(af[i], bf2[j], acc[i][j], 0, 0, 0);
        }
    }
#pragma unroll
    for (int j = 0; j < 2; ++j) {
        int col = n0 + wid*32 + j*16 + l16;
        float bv = bias[col];
#pragma unroll
        for (int i = 0; i < 4; ++i) {
            int rowb = m0 + i*16 + quad*4;
#pragma unroll
            for (int r = 0; r < 4; ++r)
                out[(size_t)(rowb + r)*512 + col] = acc[i][j][r] + bv;
        }
    }
}

// ---------------------------------------------------------------------------
extern "C" void kernel_launch(void* const* d_in, const int* in_sizes, int n_in,
                              void* d_out, int out_size, void* d_ws, size_t ws_size,
                              hipStream_t stream)
{
    (void)in_sizes; (void)n_in; (void)out_size; (void)ws_size;
    const float* x  = (const float*)d_in[0];
    const float* w3 = (const float*)d_in[1];
    const float* w5 = (const float*)d_in[2];
    const float* fw = (const float*)d_in[3];
    const float* fb = (const float*)d_in[4];
    float* out = (float*)d_out;

    const size_t SZP = (size_t)NBATCH * LSEQ * DPAD;    // padded rows
    u16* vs   = (u16*)d_ws;        // [N][L][520]
    u16* vt   = vs   + SZP;
    u16* cat  = vt   + SZP;        // [N*L][1024]
    u16* wb   = cat  + (size_t)NBATCH*LSEQ*1024;   // [512][1024] bf16

    cast_w     <<<512, 256, 0, stream>>>(fw, wb);
    conv_route <<<8192, 256, 0, stream>>>(x, w3, w5, vs, vt);
    attn       <<<dim3(32, 16), 256, 0, stream>>>(vs, vt, cat);
    fusion_gemm<<<dim3(256, 4), 256, 0, stream>>>(cat, wb, fb, out);
}

// Round 5
// 171.393 us; speedup vs baseline: 1.0723x; 1.0347x over previous
//
#include <hip/hip_runtime.h>

// ---------------------------------------------------------------------------
// capsule_87840671138361: conv->routing->attention->fusion, MI355X (gfx950)
// R12 changes vs R11:
//  - conv_route: dynamic-routing scalar iteration DEDUPLICATED. R11 ran the
//    identical 6-in/4-out recurrence on all 128 threads of a position
//    (VALUBusy 70%, ~half of it the routing chain: IEEE div/sqrt expand to
//    ~10-inst sequences). Now threads 0-1 (2 lanes of wave 0, one per
//    position) compute it and publish 4 folded weights via LDS; waves 1-3
//    skip the body via execz. Routing divides/sqrts use v_rcp_f32 /
//    v_sqrt_f32 (~1 ulp; bf16 rounding dominates) to halve the serial
//    chain other waves wait on. Apply phase uses pre-folded weights.
//  - attn / fusion_gemm / cast_w byte-identical to R11 (which moved both
//    under 41.4us: depth-2 prefetch gemm, double-buffered-K attn).
// ---------------------------------------------------------------------------

typedef short     bf16x8 __attribute__((ext_vector_type(8)));  // MFMA A/B frag
typedef float     f32x4  __attribute__((ext_vector_type(4)));  // MFMA C/D frag
typedef unsigned short u16;
typedef u16       u16x8  __attribute__((ext_vector_type(8)));
typedef u16       u16x4  __attribute__((ext_vector_type(4)));
typedef unsigned int u32;
typedef u32       u32x4  __attribute__((ext_vector_type(4)));

#define NBATCH 8
#define LSEQ   2048
#define DCH    512
#define DPAD   520      // padded global row stride (elems): 1040B
#define VSTR   40       // Vs LDS row stride (u16): 80B -> bank-even b128
#define DECAYF 0.2f
#define WTILES 4        // 64-key min window; truncated mass ~4e-5 relative

typedef const __attribute__((address_space(1))) unsigned char* gas_t;
typedef __attribute__((address_space(3))) unsigned char* las_t;
__device__ __forceinline__ void dma16(const void* g, void* l) {
    __builtin_amdgcn_global_load_lds((gas_t)g, (las_t)l, 16, 0, 0);
}

__device__ __forceinline__ u16 f2bf(float f) {
    unsigned int u = __float_as_uint(f);
    u += 0x7fffu + ((u >> 16) & 1u);   // RNE; inputs never NaN
    return (u16)(u >> 16);
}

__device__ __forceinline__ void wave_sum6(float& a, float& b, float& c,
                                          float& d, float& e, float& f) {
#pragma unroll
    for (int m = 1; m < 64; m <<= 1) {
        float ta = __shfl_xor(a, m, 64);
        float tb = __shfl_xor(b, m, 64);
        float tc = __shfl_xor(c, m, 64);
        float td = __shfl_xor(d, m, 64);
        float te = __shfl_xor(e, m, 64);
        float tf = __shfl_xor(f, m, 64);
        a += ta; b += tb; c += tc; d += td; e += te; f += tf;
    }
}

// ---------------------------------------------------------------------------
// Kernel 1: causal depthwise conv (k=3,5) + 2x dynamic routing via Gram dots.
// Two half-waves per (n,l); lane owns 4 channels. R12: routing dedup'd to
// one lane per position (threads 0-1), fast rcp/sqrt, folded weights.
// ---------------------------------------------------------------------------
__global__ __launch_bounds__(256) void conv_route(
    const float* __restrict__ x, const float* __restrict__ w3, const float* __restrict__ w5,
    u16* __restrict__ vs, u16* __restrict__ vt)
{
    const int wid  = threadIdx.x >> 6;           // 0..3
    const int lane = threadIdx.x & 63;
    const int pp   = wid >> 1;                   // position within block (0..1)
    const int half = wid & 1;                    // channel half
    const int p = blockIdx.x * 2 + pp;           // 16384 positions
    const int n = p >> 11, l = p & (LSEQ - 1);
    const int c0 = half * 256 + lane * 4;

    float xm[5][4];                              // xm[j][i] = x[l-j][c0+i]
#pragma unroll
    for (int j = 0; j < 5; ++j) {
        int ll = l - j;
        if (ll >= 0) {                           // wave-uniform branch
            float4 a = *(const float4*)(x + ((size_t)(n*LSEQ + ll))*DCH + c0);
            xm[j][0]=a.x; xm[j][1]=a.y; xm[j][2]=a.z; xm[j][3]=a.w;
        } else {
#pragma unroll
            for (int i = 0; i < 4; ++i) xm[j][i] = 0.f;
        }
    }
    float f3[12], f5[20];
#pragma unroll
    for (int k = 0; k < 3; ++k) ((float4*)f3)[k] = ((const float4*)(w3 + (size_t)c0*3))[k];
#pragma unroll
    for (int k = 0; k < 5; ++k) ((float4*)f5)[k] = ((const float4*)(w5 + (size_t)c0*5))[k];

    float t3[4], t5[4], a0[4], a1[4];
#pragma unroll
    for (int i = 0; i < 4; ++i) {
        t3[i] = f3[i*3+0]*xm[2][i] + f3[i*3+1]*xm[1][i] + f3[i*3+2]*xm[0][i];
        t5[i] = f5[i*5+0]*xm[4][i] + f5[i*5+1]*xm[3][i] + f5[i*5+2]*xm[2][i]
              + f5[i*5+3]*xm[1][i] + f5[i*5+4]*xm[0][i];
        a0[i] = xm[0][i] - t3[i];
        a1[i] = xm[0][i] - t5[i];
    }

    float A1=0.f, B1=0.f, C1=0.f, A2=0.f, B2=0.f, C2=0.f;
#pragma unroll
    for (int i = 0; i < 4; ++i) {
        A1 += a0[i]*a0[i]; B1 += a0[i]*a1[i]; C1 += a1[i]*a1[i];
        A2 += t3[i]*t3[i]; B2 += t3[i]*t5[i]; C2 += t5[i]*t5[i];
    }
    wave_sum6(A1, B1, C1, A2, B2, C2);

    __shared__ float red[2][2][6];
    __shared__ float rout[2][4];                 // folded weights per position
    if (lane == 0) {
        red[pp][half][0] = A1; red[pp][half][1] = B1; red[pp][half][2] = C1;
        red[pp][half][3] = A2; red[pp][half][4] = B2; red[pp][half][5] = C2;
    }
    __syncthreads();

    // routing on 2 lanes total (thread 0 -> pos 0, thread 1 -> pos 1);
    // waves 1-3 skip via execz. Fast v_rcp/v_sqrt shorten the serial chain.
    if (threadIdx.x < 2) {
        const int q = threadIdx.x;
        float rA1 = red[q][0][0] + red[q][1][0];
        float rB1 = red[q][0][1] + red[q][1][1];
        float rC1 = red[q][0][2] + red[q][1][2];
        float rA2 = red[q][0][3] + red[q][1][3];
        float rB2 = red[q][0][4] + red[q][1][4];
        float rC2 = red[q][0][5] + red[q][1][5];

        float ba0=0.f, ba1=0.f, bb0=0.f, bb1=0.f;
        float ca0=0.5f, ca1=0.5f, sca=0.f, cb0=0.5f, cb1=0.5f, scb=0.f;
#pragma unroll
        for (int it = 0; it < 3; ++it) {
            float mxa = fmaxf(ba0, ba1), mxb = fmaxf(bb0, bb1);
            float ea0 = __expf(ba0-mxa), ea1 = __expf(ba1-mxa);
            float eb0 = __expf(bb0-mxb), eb1 = __expf(bb1-mxb);
            float ia = __builtin_amdgcn_rcpf(ea0+ea1);
            float ib = __builtin_amdgcn_rcpf(eb0+eb1);
            ca0 = ea0*ia; ca1 = ea1*ia; cb0 = eb0*ib; cb1 = eb1*ib;
            float na = ca0*ca0*rA1 + 2.f*ca0*ca1*rB1 + ca1*ca1*rC1;
            float nb = cb0*cb0*rA2 + 2.f*cb0*cb1*rB2 + cb1*cb1*rC2;
            float sa = __builtin_amdgcn_sqrtf(na);
            float sb = __builtin_amdgcn_sqrtf(nb);
            sca = na * __builtin_amdgcn_rcpf((1.f + na) * (sa + 1e-9f));
            scb = nb * __builtin_amdgcn_rcpf((1.f + nb) * (sb + 1e-9f));
            if (it < 2) {
                ba0 += sca*(ca0*rA1 + ca1*rB1);
                ba1 += sca*(ca0*rB1 + ca1*rC1);
                bb0 += scb*(cb0*rA2 + cb1*rB2);
                bb1 += scb*(cb0*rB2 + cb1*rC2);
            }
        }
        rout[q][0] = sca*ca0; rout[q][1] = sca*ca1;
        rout[q][2] = scb*cb0; rout[q][3] = scb*cb1;
    }
    __syncthreads();

    const float wa0 = rout[pp][0], wa1 = rout[pp][1];
    const float wb0 = rout[pp][2], wb1 = rout[pp][3];
    u16x4 pa, pb;
#pragma unroll
    for (int i = 0; i < 4; ++i) {
        pa[i] = f2bf(wa0*a0[i] + wa1*a1[i]);
        pb[i] = f2bf(wb0*t3[i] + wb1*t5[i]);
    }
    *(u16x4*)(vs + (size_t)p*DPAD + c0) = pa;
    *(u16x4*)(vt + (size_t)p*DPAD + c0) = pb;
}

// ---------------------------------------------------------------------------
// Kernel 2: windowed causal attention; V^T built in-LDS from Ks.
// grid (32 strips, 16 instances), 256 threads (4 waves), 64 q-rows/block.
// R10/R11: Ks double-buffered, counted vmcnt, raw barriers, b32 transpose.
// ---------------------------------------------------------------------------
__global__ __launch_bounds__(256) void attn(
    const u16* __restrict__ vs, const u16* __restrict__ vt,
    u16* __restrict__ cat)
{
    __shared__ u16 KsB[2][18432];            // 2 x 36KB (32 rows x 1040B + slack)
    __shared__ u16 Vs[DCH*VSTR];             // 40 KB, [ch][40] slot-interleaved
    __shared__ unsigned int Ps32[4][16][20]; // per-wave P, packed pairs

    const int inst = blockIdx.y;
    const int t = inst >> 3, n = inst & 7;
    const u16* src = (t ? vt : vs) + (size_t)n * LSEQ * DPAD;

    const int bx = blockIdx.x;
    const int r0 = (((bx & 7) << 2) | (bx >> 3)) * 64;   // XCD swizzle

    const int tid  = threadIdx.x;
    const int wid  = tid >> 6, lane = tid & 63;
    const int l16  = lane & 15, quad = lane >> 4;

    // Q A-frags register-resident
    bf16x8 qf[16];
    {
        const u16* qp = src + (size_t)(r0 + wid*16 + l16) * DPAD + quad*8;
#pragma unroll
        for (int kc = 0; kc < 16; ++kc) qf[kc] = *(const bf16x8*)(qp + kc*32);
    }

    f32x4 O[32];
#pragma unroll
    for (int i = 0; i < 32; ++i) O[i] = (f32x4){0.f, 0.f, 0.f, 0.f};
    f32x4 O2 = {0.f, 0.f, 0.f, 0.f};       // row sums via ones-MFMA

    bf16x8 ones8;
#pragma unroll
    for (int i = 0; i < 8; ++i) ones8[i] = (short)0x3F80;   // bf16 1.0

    const int kb_hi = (r0 >> 5) + 1;
    const int kb_lo = (kb_hi >= WTILES) ? kb_hi - (WTILES-1) : 0;

    // uniform 9 loads/wave; chunks 33..35 re-read chunk 0 (tile = 32.5
    // chunks) so the source never leaves the tile; their LDS dest is slack.
    auto stageK = [&](int kbt, int buf) {
        const u16* gK = src + (size_t)kbt * 32 * DPAD;
#pragma unroll
        for (int j = 0; j < 9; ++j) {
            int i = wid + 4*j;                 // 0..35
            int is = (i < 33) ? i : 0;         // safe source chunk
            dma16(gK + is*512 + lane*8, KsB[buf] + i*512);
        }
    };

    // prologue: K(kb_lo), K(kb_lo+1) in flight (kb_lo+1 <= kb_hi always)
    stageK(kb_lo,     0);
    stageK(kb_lo + 1, 1);

    for (int kb = kb_lo; kb <= kb_hi; ++kb) {
        // drain K(kb) only; K(kb+1) stays in flight across the barrier
        if (kb < kb_hi) asm volatile("s_waitcnt vmcnt(9)" ::: "memory");
        else            asm volatile("s_waitcnt vmcnt(0)" ::: "memory");
        __builtin_amdgcn_s_barrier();          // K(kb) landed for all waves;
        asm volatile("" ::: "memory");         //   prev Phase B done with Vs
        const u16* K = KsB[(kb - kb_lo) & 1];

        // Phase A: S[16x32] = Q * K^T, 4 independent 8-deep chains
        f32x4 S0a = {0.f,0.f,0.f,0.f}, S1a = {0.f,0.f,0.f,0.f};
        f32x4 S0b = {0.f,0.f,0.f,0.f}, S1b = {0.f,0.f,0.f,0.f};
#pragma unroll
        for (int kc = 0; kc < 8; ++kc) {
            bf16x8 b0 = *(const bf16x8*)(K + (size_t)l16*DPAD + kc*32 + quad*8);
            bf16x8 b1 = *(const bf16x8*)(K + (size_t)(16+l16)*DPAD + kc*32 + quad*8);
            S0a = __builtin_amdgcn_mfma_f32_16x16x32_bf16(qf[kc], b0, S0a, 0, 0, 0);
            S1a = __builtin_amdgcn_mfma_f32_16x16x32_bf16(qf[kc], b1, S1a, 0, 0, 0);
        }
#pragma unroll
        for (int kc = 8; kc < 16; ++kc) {
            bf16x8 b0 = *(const bf16x8*)(K + (size_t)l16*DPAD + kc*32 + quad*8);
            bf16x8 b1 = *(const bf16x8*)(K + (size_t)(16+l16)*DPAD + kc*32 + quad*8);
            S0b = __builtin_amdgcn_mfma_f32_16x16x32_bf16(qf[kc], b0, S0b, 0, 0, 0);
            S1b = __builtin_amdgcn_mfma_f32_16x16x32_bf16(qf[kc], b1, S1b, 0, 0, 0);
        }
        f32x4 S0 = S0a + S0b, S1 = S1a + S1b;

        // in-LDS transpose, b32-pair form: thread owns chs {2*tid, 2*tid+1}.
        // 32 ds_read_b32 (conflict-free) + pack + 8 b128 writes per thread
        // (was 64 scalar ds_read_u16). Vs[ch][40]: slot s <- key (s>>1)+16(s&1)
        {
            const int ch2 = tid * 2;
#pragma unroll
            for (int g = 0; g < 4; ++g) {
                u32 pe[4], po[4];
#pragma unroll
                for (int j = 0; j < 4; ++j) {
                    u32 lo = *(const u32*)(K + (size_t)(g*4 + j)      * DPAD + ch2);
                    u32 hi = *(const u32*)(K + (size_t)(g*4 + j + 16) * DPAD + ch2);
                    pe[j] = (lo & 0xffffu) | (hi << 16);
                    po[j] = (lo >> 16)     | (hi & 0xffff0000u);
                }
                *(u32x4*)(Vs + (size_t)ch2*VSTR + g*8)       = (u32x4){pe[0],pe[1],pe[2],pe[3]};
                *(u32x4*)(Vs + (size_t)(ch2+1)*VSTR + g*8)   = (u32x4){po[0],po[1],po[2],po[3]};
            }
        }

        // fixed-max softmax: p = exp(s - 1 - 0.2*d), zero outside causal window
        const int rowg = r0 + wid*16 + quad*4;
#pragma unroll
        for (int r = 0; r < 4; ++r) {
            int row = rowg + r;
            int d0  = row - (kb*32 + l16);
            int d1  = d0 - 16;
            float p0 = (d0 >= 0) ? __expf(fmaf(-DECAYF, (float)d0, S0[r] - 1.f)) : 0.f;
            float p1 = (d1 >= 0) ? __expf(fmaf(-DECAYF, (float)d1, S1[r] - 1.f)) : 0.f;
            Ps32[wid][quad*4 + r][l16] = ((unsigned)f2bf(p1) << 16) | (unsigned)f2bf(p0);
        }

        asm volatile("s_waitcnt lgkmcnt(0)" ::: "memory");  // Vs/Ps writes done
        __builtin_amdgcn_s_barrier();          // Vs complete; Ks[buf] free
        asm volatile("" ::: "memory");
        // K(kb+2) DMA into the buffer just freed; overlaps Phase B + next A
        if (kb + 2 <= kb_hi) stageK(kb + 2, (kb - kb_lo) & 1);

        // Phase B: O += P * V (slot-interleaved, consistent in Ps & Vs)
        bf16x8 pf = *(const bf16x8*)(&Ps32[wid][l16][quad*4]);
#pragma unroll
        for (int ct = 0; ct < 32; ++ct) {
            bf16x8 vf = *(const bf16x8*)(Vs + (size_t)(ct*16 + l16)*VSTR + quad*8);
            O[ct] = __builtin_amdgcn_mfma_f32_16x16x32_bf16(pf, vf, O[ct], 0, 0, 0);
        }
        O2 = __builtin_amdgcn_mfma_f32_16x16x32_bf16(pf, ones8, O2, 0, 0, 0);
    }

    // epilogue: O /= rowsum, write bf16 into cat
    float inv[4];
#pragma unroll
    for (int r = 0; r < 4; ++r) inv[r] = 1.f / O2[r];
    const size_t rowbase = (size_t)n * LSEQ + r0 + wid*16 + quad*4;
    const int colbase = t * 512 + l16;
#pragma unroll
    for (int ct = 0; ct < 32; ++ct) {
#pragma unroll
        for (int r = 0; r < 4; ++r)
            cat[(rowbase + r) * 1024 + colbase + ct*16] = f2bf(O[ct][r] * inv[r]);
    }
}

// ---------------------------------------------------------------------------
// Kernel 3: cast fusion_w fp32 -> bf16
// ---------------------------------------------------------------------------
__global__ __launch_bounds__(256) void cast_w(const float* __restrict__ w, u16* __restrict__ wb)
{
    int id = blockIdx.x * 256 + threadIdx.x;   // 131072 float4 chunks
    float4 f = ((const float4*)w)[id];
    u16x4 o;
    o[0] = f2bf(f.x); o[1] = f2bf(f.y); o[2] = f2bf(f.z); o[3] = f2bf(f.w);
    ((u16x4*)wb)[id] = o;
}

// ---------------------------------------------------------------------------
// Kernel 4: out[16384,512] = cat @ W^T + bias. 64x128 tiles, BK=64,
// dma16 staging with XOR-swizzled chunk mapping (swizzle via source addr).
// R10/R11: depth-2 prefetch, 3 buffers, counted vmcnt(6) (never 0 mid-loop).
// ---------------------------------------------------------------------------
__global__ __launch_bounds__(256) void fusion_gemm(
    const u16* __restrict__ A, const u16* __restrict__ Wb,
    const float* __restrict__ bias, float* __restrict__ out)
{
    __shared__ u16 As[3][64*64];    // 24 KB
    __shared__ u16 Bs[3][128*64];   // 48 KB
    const int m0 = blockIdx.x * 64;
    const int n0 = blockIdx.y * 128;
    const int tid = threadIdx.x;
    const int wid = tid >> 6, lane = tid & 63;
    const int l16 = lane & 15, quad = lane >> 4;

    f32x4 acc[4][2];
#pragma unroll
    for (int i = 0; i < 4; ++i)
#pragma unroll
        for (int j = 0; j < 2; ++j) acc[i][j] = (f32x4){0.f, 0.f, 0.f, 0.f};

    auto stage = [&](int kb_, int b_) {        // 6 dma16 per wave
#pragma unroll
        for (int i = 0; i < 2; ++i) {
            int q = i*256 + tid, r = q >> 3, kp = q & 7;
            int kl = kp ^ (r & 7);
            dma16(A + (size_t)(m0 + r)*1024 + kb_*64 + kl*8, As[b_] + q*8);
        }
#pragma unroll
        for (int i = 0; i < 4; ++i) {
            int q = i*256 + tid, r = q >> 3, kp = q & 7;
            int kl = kp ^ (r & 7);
            dma16(Wb + (size_t)(n0 + r)*1024 + kb_*64 + kl*8, Bs[b_] + q*8);
        }
    };

    stage(0, 0);
    stage(1, 1);
    for (int kb = 0; kb < 16; ++kb) {
        const int b = kb % 3;
        // drain tile kb's 6 loads; leave tile kb+1's 6 in flight
        if (kb < 15) asm volatile("s_waitcnt vmcnt(6)" ::: "memory");
        else         asm volatile("s_waitcnt vmcnt(0)" ::: "memory");
        __builtin_amdgcn_s_barrier();          // all waves' kb-DMA landed;
        asm volatile("" ::: "memory");         //   all done reading buf kb-1
        if (kb < 14) stage(kb + 2, (kb + 2) % 3);   // overlaps 2 compute phases
#pragma unroll
        for (int k2 = 0; k2 < 2; ++k2) {
            const int kl = k2*4 + quad;
            bf16x8 af[4], bf2[2];
#pragma unroll
            for (int i = 0; i < 4; ++i) {
                int r = i*16 + l16;
                af[i] = *(const bf16x8*)(As[b] + r*64 + (kl ^ (r & 7))*8);
            }
#pragma unroll
            for (int j = 0; j < 2; ++j) {
                int r = wid*32 + j*16 + l16;
                bf2[j] = *(const bf16x8*)(Bs[b] + r*64 + (kl ^ (r & 7))*8);
            }
#pragma unroll
            for (int i = 0; i < 4; ++i)
#pragma unroll
                for (int j = 0; j < 2; ++j)
                    acc[i][j] = __builtin_amdgcn_mfma_f32_16x16x32_bf16(af[i], bf2[j], acc[i][j], 0, 0, 0);
        }
    }
#pragma unroll
    for (int j = 0; j < 2; ++j) {
        int col = n0 + wid*32 + j*16 + l16;
        float bv = bias[col];
#pragma unroll
        for (int i = 0; i < 4; ++i) {
            int rowb = m0 + i*16 + quad*4;
#pragma unroll
            for (int r = 0; r < 4; ++r)
                out[(size_t)(rowb + r)*512 + col] = acc[i][j][r] + bv;
        }
    }
}

// ---------------------------------------------------------------------------
extern "C" void kernel_launch(void* const* d_in, const int* in_sizes, int n_in,
                              void* d_out, int out_size, void* d_ws, size_t ws_size,
                              hipStream_t stream)
{
    (void)in_sizes; (void)n_in; (void)out_size; (void)ws_size;
    const float* x  = (const float*)d_in[0];
    const float* w3 = (const float*)d_in[1];
    const float* w5 = (const float*)d_in[2];
    const float* fw = (const float*)d_in[3];
    const float* fb = (const float*)d_in[4];
    float* out = (float*)d_out;

    const size_t SZP = (size_t)NBATCH * LSEQ * DPAD;    // padded rows
    u16* vs   = (u16*)d_ws;        // [N][L][520]
    u16* vt   = vs   + SZP;
    u16* cat  = vt   + SZP;        // [N*L][1024]
    u16* wb   = cat  + (size_t)NBATCH*LSEQ*1024;   // [512][1024] bf16

    cast_w     <<<512, 256, 0, stream>>>(fw, wb);
    conv_route <<<8192, 256, 0, stream>>>(x, w3, w5, vs, vt);
    attn       <<<dim3(32, 16), 256, 0, stream>>>(vs, vt, cat);
    fusion_gemm<<<dim3(256, 4), 256, 0, stream>>>(cat, wb, fb, out);
}